// Round 6
// baseline (1104.181 us; speedup 1.0000x reference)
//
#include <hip/hip_runtime.h>

typedef _Float16 h8v __attribute__((ext_vector_type(8)));
typedef _Float16 h2v __attribute__((ext_vector_type(2)));
typedef float f4v __attribute__((ext_vector_type(4)));

#define RS  136   // LDS row stride in halves (272 B = 16B multiple)
#define RSD 68    // dwords

__device__ __forceinline__ unsigned pk2f(float a, float b) {
  unsigned short ha = __builtin_bit_cast(unsigned short, (_Float16)a);
  unsigned short hb = __builtin_bit_cast(unsigned short, (_Float16)b);
  return (unsigned)ha | ((unsigned)hb << 16);
}
__device__ __forceinline__ float2 upk(unsigned u) {
  _Float16 lo = __builtin_bit_cast(_Float16, (unsigned short)(u & 0xffffu));
  _Float16 hi = __builtin_bit_cast(_Float16, (unsigned short)(u >> 16));
  return make_float2((float)lo, (float)hi);
}
__device__ __forceinline__ unsigned pkadd(unsigned a, unsigned b) {
  h2v x = __builtin_bit_cast(h2v, a), y = __builtin_bit_cast(h2v, b);
  h2v r = x + y;
  return __builtin_bit_cast(unsigned, r);
}

// Wlf[o*128 + k] = f16(Wl[o][k]), zero-padded to [112][128]
__global__ void prep_kernel(const float* __restrict__ Wl,
                            unsigned short* __restrict__ Wlf) {
  int i = blockIdx.x * 256 + threadIdx.x;
  if (i < 112 * 128) {
    int o = i >> 7, k = i & 127;
    _Float16 v = (_Float16)0.f;
    if (o < 100 && k < 100) v = (_Float16)Wl[o * 100 + k];
    Wlf[i] = __builtin_bit_cast(unsigned short, v);
  }
}

// Run nLvl tree levels in LDS. S holds n0 summed-child rows (f16, RS stride,
// halves >=100 zero). B-frags (Wl) preloaded in VGPRs: wave w owns col-tiles
// {2w, 2w+1} (wave 3: tile 6 only). Per level: MFMA -> H (relu, f16), barrier,
// pairsum H->S + proj H->out, barrier.
__device__ __forceinline__ void run_levels(
    _Float16* S, _Float16* H, const float* WpS,
    const h8v (&Bf)[2][4], const float (&bias)[2], int nT,
    int firstLvl, int nLvl, int n0, int blk,
    const float* __restrict__ bp, float* __restrict__ out,
    int tid, int lane, int wave) {
  const int quad = lane >> 4, c16 = lane & 15;
  unsigned* Hd = (unsigned*)H;
  unsigned* Sd = (unsigned*)S;
  int n = n0;
  for (int j = 0; j < nLvl; ++j) {
    int lvl = firstLvl + j;
    int tiles = (n + 15) >> 4;
    for (int rt = 0; rt < tiles; ++rt) {
      int rb = rt << 4;
      const _Float16* arow = S + (rb + c16) * RS + quad * 8;
      h8v Af0 = *(const h8v*)(arow);
      h8v Af1 = *(const h8v*)(arow + 32);
      h8v Af2 = *(const h8v*)(arow + 64);
      h8v Af3 = *(const h8v*)(arow + 96);
      for (int t = 0; t < nT; ++t) {
        int ct = wave * 2 + t;
        f4v acc = {bias[t], bias[t], bias[t], bias[t]};
        acc = __builtin_amdgcn_mfma_f32_16x16x32_f16(Af0, Bf[t][0], acc, 0, 0, 0);
        acc = __builtin_amdgcn_mfma_f32_16x16x32_f16(Af1, Bf[t][1], acc, 0, 0, 0);
        acc = __builtin_amdgcn_mfma_f32_16x16x32_f16(Af2, Bf[t][2], acc, 0, 0, 0);
        acc = __builtin_amdgcn_mfma_f32_16x16x32_f16(Af3, Bf[t][3], acc, 0, 0, 0);
        #pragma unroll
        for (int rg = 0; rg < 4; ++rg) {
          float v = fmaxf(acc[rg], 0.f);
          unsigned hv = (unsigned)__builtin_bit_cast(unsigned short, (_Float16)v);
          unsigned po = __shfl_xor(hv, 1, 64);
          if ((c16 & 1) == 0) {
            int row = rb + quad * 4 + rg;
            Hd[row * RSD + ct * 8 + (c16 >> 1)] = hv | (po << 16);
          }
        }
      }
    }
    __syncthreads();
    if (n > 1) {  // pairsum H -> S for next level (halves 100..111 stay 0)
      int nn = n >> 1;
      for (int i = tid; i < nn * 56; i += 256) {
        int nd = i / 56, d = i - nd * 56;
        Sd[nd * RSD + d] = pkadd(Hd[(2 * nd) * RSD + d], Hd[(2 * nd + 1) * RSD + d]);
      }
    }
    if (tid < n) {  // projection of this level's h rows
      const unsigned* hr = Hd + tid * RSD;
      float p0 = bp[0], p1 = bp[1];
      #pragma unroll 5
      for (int p = 0; p < 50; ++p) {
        float2 h2 = upk(hr[p]);
        p0 = fmaf(h2.x, WpS[2 * p], fmaf(h2.y, WpS[2 * p + 1], p0));
        p1 = fmaf(h2.x, WpS[100 + 2 * p], fmaf(h2.y, WpS[100 + 2 * p + 1], p1));
      }
      long g = (long)blk * n + tid;
      long pos = ((g + 1) << (lvl + 1)) - 2 - __popc((unsigned)g);
      out[2 * pos] = p0; out[2 * pos + 1] = p1;
    }
    __syncthreads();
    n >>= 1;
  }
}

__device__ __forceinline__ void load_bfrags(
    const unsigned short* __restrict__ Wlf, const float* __restrict__ bl,
    h8v (&Bf)[2][4], float (&bias)[2], int nT, int wave, int quad, int c16) {
  for (int t = 0; t < nT; ++t) {
    int ct = wave * 2 + t, col = ct * 16 + c16;
    bias[t] = (col < 100) ? 2.0f * bl[col] : 0.f;
    const _Float16* wrow = (const _Float16*)Wlf + col * 128 + quad * 8;
    Bf[t][0] = *(const h8v*)(wrow);
    Bf[t][1] = *(const h8v*)(wrow + 32);
    Bf[t][2] = *(const h8v*)(wrow + 64);
    Bf[t][3] = *(const h8v*)(wrow + 96);
  }
}

// Leaf kernel: 256 leaves/block. Lvl-0 proj (fp32) + levels 1..8 via MFMA.
// Writes the block's lvl-8 row (56 dwords packed f16) to h8g.
__global__ __launch_bounds__(256) void leaf_kernel(
    const int* __restrict__ word_ids, const float* __restrict__ emb,
    const unsigned short* __restrict__ Wlf, const float* __restrict__ bl,
    const float* __restrict__ Wp, const float* __restrict__ bp,
    unsigned* __restrict__ h8g, float* __restrict__ out) {
  __shared__ _Float16 S[128 * RS];
  __shared__ _Float16 H[128 * RS];
  __shared__ float WpS[200];
  const int tid = threadIdx.x, lane = tid & 63;
  const int wave = __builtin_amdgcn_readfirstlane(tid >> 6);
  const int quad = lane >> 4, c16 = lane & 15;
  const int blk = blockIdx.x;
  unsigned* Sd = (unsigned*)S;

  if (tid < 200) WpS[tid] = Wp[tid];
  // zero S pad dwords [50,64) per row
  for (int i = tid; i < 128 * 14; i += 256)
    Sd[(i / 14) * RSD + 50 + (i % 14)] = 0;

  // load this thread's leaf embedding row
  int g = blk * 256 + tid;
  float r[100];
  {
    const float4* row4 = (const float4*)(emb + (size_t)word_ids[g] * 100);
    #pragma unroll
    for (int q = 0; q < 25; ++q) {
      float4 v = row4[q];
      r[4*q] = v.x; r[4*q+1] = v.y; r[4*q+2] = v.z; r[4*q+3] = v.w;
    }
  }
  // leaf projection (fp32 exact inputs)
  {
    const float4* wp0 = (const float4*)Wp;
    const float4* wp1 = (const float4*)(Wp + 100);
    float p0 = bp[0], p1 = bp[1];
    #pragma unroll
    for (int q = 0; q < 25; ++q) {
      float4 a = wp0[q], b = wp1[q];
      p0 = fmaf(r[4*q],a.x,p0); p0 = fmaf(r[4*q+1],a.y,p0);
      p0 = fmaf(r[4*q+2],a.z,p0); p0 = fmaf(r[4*q+3],a.w,p0);
      p1 = fmaf(r[4*q],b.x,p1); p1 = fmaf(r[4*q+1],b.y,p1);
      p1 = fmaf(r[4*q+2],b.z,p1); p1 = fmaf(r[4*q+3],b.w,p1);
    }
    long pos = 2L * g - __popc((unsigned)g);
    out[2*pos] = p0; out[2*pos+1] = p1;
  }
  // pair-sum adjacent leaves -> S rows (f16 packed, k-contiguous)
  #pragma unroll
  for (int d = 0; d < 50; ++d) {
    float s0 = r[2*d]   + __shfl_xor(r[2*d],   1, 64);
    float s1 = r[2*d+1] + __shfl_xor(r[2*d+1], 1, 64);
    if ((tid & 1) == 0) Sd[(tid >> 1) * RSD + d] = pk2f(s0, s1);
  }

  h8v Bf[2][4]; float bias[2];
  int nT = (wave < 3) ? 2 : 1;
  load_bfrags(Wlf, bl, Bf, bias, nT, wave, quad, c16);
  __syncthreads();

  run_levels(S, H, WpS, Bf, bias, nT, 1, 8, 128, blk, bp, out, tid, lane, wave);

  unsigned* Hd = (unsigned*)H;
  if (tid < 56) h8g[blk * 56 + tid] = Hd[tid];   // lvl-8 h row
}

// Generic tree kernel: block reads 2*n0 packed rows from hsrc, pairsums into S,
// runs nLvl levels from firstLvl; optionally writes last-level rows to hdst.
__global__ __launch_bounds__(256) void tree_kernel(
    const unsigned* __restrict__ hsrc, unsigned* __restrict__ hdst,
    const unsigned short* __restrict__ Wlf, const float* __restrict__ bl,
    const float* __restrict__ Wp, const float* __restrict__ bp,
    float* __restrict__ out, int firstLvl, int nLvl, int n0, int wantH) {
  __shared__ _Float16 S[64 * RS];
  __shared__ _Float16 H[64 * RS];
  __shared__ float WpS[200];
  const int tid = threadIdx.x, lane = tid & 63;
  const int wave = __builtin_amdgcn_readfirstlane(tid >> 6);
  const int quad = lane >> 4, c16 = lane & 15;
  const int blk = blockIdx.x;
  unsigned* Sd = (unsigned*)S;

  if (tid < 200) WpS[tid] = Wp[tid];
  for (int i = tid; i < n0 * 56; i += 256) {
    int nd = i / 56, d = i - nd * 56;
    Sd[nd * RSD + d] = pkadd(hsrc[((size_t)blk * 2 * n0 + 2 * nd) * 56 + d],
                             hsrc[((size_t)blk * 2 * n0 + 2 * nd + 1) * 56 + d]);
  }
  for (int i = tid; i < n0 * 8; i += 256)
    Sd[(i / 8) * RSD + 56 + (i % 8)] = 0;

  h8v Bf[2][4]; float bias[2];
  int nT = (wave < 3) ? 2 : 1;
  load_bfrags(Wlf, bl, Bf, bias, nT, wave, quad, c16);
  __syncthreads();

  run_levels(S, H, WpS, Bf, bias, nT, firstLvl, nLvl, n0, blk, bp, out, tid, lane, wave);

  if (wantH) {
    int R = n0 >> (nLvl - 1);   // rows produced at last level
    unsigned* Hd = (unsigned*)H;
    for (int i = tid; i < R * 56; i += 256)
      hdst[(size_t)blk * R * 56 + i] = Hd[(i / 56) * RSD + (i % 56)];
  }
}

extern "C" void kernel_launch(void* const* d_in, const int* in_sizes, int n_in,
                              void* d_out, int out_size, void* d_ws, size_t ws_size,
                              hipStream_t stream) {
  const int*   word_ids = (const int*)  d_in[0];
  const float* emb      = (const float*)d_in[1];
  const float* Wl       = (const float*)d_in[2];
  const float* bl       = (const float*)d_in[3];
  const float* Wp       = (const float*)d_in[4];
  const float* bp       = (const float*)d_in[5];
  float* out = (float*)d_out;

  unsigned short* Wlf = (unsigned short*)d_ws;                    // 28672 B
  unsigned* h8  = (unsigned*)((char*)d_ws + 32768);               // 512*56 dw
  unsigned* h15 = (unsigned*)((char*)d_ws + 32768 + 131072);      // 4*56 dw

  prep_kernel<<<56, 256, 0, stream>>>(Wl, Wlf);
  // lvls 0..8: 512 blocks x 256 leaves -> h8 (512 rows)
  leaf_kernel<<<512, 256, 0, stream>>>(word_ids, emb, Wlf, bl, Wp, bp, h8, out);
  // lvls 9..15: 4 blocks x 64 lvl-9 nodes -> h15 (4 rows)
  tree_kernel<<<4, 256, 0, stream>>>(h8, h15, Wlf, bl, Wp, bp, out, 9, 7, 64, 1);
  // lvls 16..17: 1 block x 2 lvl-16 nodes
  tree_kernel<<<1, 256, 0, stream>>>(h15, nullptr, Wlf, bl, Wp, bp, out, 16, 2, 2, 0);
}

// Round 7
// 173.460 us; speedup vs baseline: 6.3656x; 6.3656x over previous
//
#include <hip/hip_runtime.h>

typedef _Float16 h8v __attribute__((ext_vector_type(8)));
typedef _Float16 h2v __attribute__((ext_vector_type(2)));
typedef float f4v __attribute__((ext_vector_type(4)));

#define RS  136   // LDS row stride in halves (272 B, 16B-aligned rows)
#define RSD 68    // row stride in dwords

__device__ __forceinline__ unsigned pk2f(float a, float b) {
  unsigned short ha = __builtin_bit_cast(unsigned short, (_Float16)a);
  unsigned short hb = __builtin_bit_cast(unsigned short, (_Float16)b);
  return (unsigned)ha | ((unsigned)hb << 16);
}
__device__ __forceinline__ float2 upk(unsigned u) {
  _Float16 lo = __builtin_bit_cast(_Float16, (unsigned short)(u & 0xffffu));
  _Float16 hi = __builtin_bit_cast(_Float16, (unsigned short)(u >> 16));
  return make_float2((float)lo, (float)hi);
}
__device__ __forceinline__ unsigned pkadd(unsigned a, unsigned b) {
  h2v x = __builtin_bit_cast(h2v, a), y = __builtin_bit_cast(h2v, b);
  h2v r = x + y;
  return __builtin_bit_cast(unsigned, r);
}

// Wlf[o*128 + k] = f16(Wl[o][k]), zero-padded to [128][128]
__global__ void prep_kernel(const float* __restrict__ Wl,
                            unsigned short* __restrict__ Wlf) {
  int i = blockIdx.x * 256 + threadIdx.x;
  if (i < 128 * 128) {
    int o = i >> 7, k = i & 127;
    _Float16 v = (_Float16)0.f;
    if (o < 100 && k < 100) v = (_Float16)Wl[o * 100 + k];
    Wlf[i] = __builtin_bit_cast(unsigned short, v);
  }
}

// Wave w owns col-tiles 2w and 2w+1 (tile 7 = all-zero pad cols). Static regs.
__device__ __forceinline__ void load_bfrags(
    const unsigned short* __restrict__ Wlf, const float* __restrict__ bl,
    h8v (&B0)[4], h8v (&B1)[4], float& bias0, float& bias1,
    int wave, int quad, int c16) {
  int col0 = (wave * 2) * 16 + c16;
  int col1 = col0 + 16;
  bias0 = (col0 < 100) ? 2.0f * bl[col0] : 0.f;
  bias1 = (col1 < 100) ? 2.0f * bl[col1] : 0.f;
  const _Float16* w0 = (const _Float16*)Wlf + col0 * 128 + quad * 8;
  const _Float16* w1 = (const _Float16*)Wlf + col1 * 128 + quad * 8;
  B0[0] = *(const h8v*)(w0);      B0[1] = *(const h8v*)(w0 + 32);
  B0[2] = *(const h8v*)(w0 + 64); B0[3] = *(const h8v*)(w0 + 96);
  B1[0] = *(const h8v*)(w1);      B1[1] = *(const h8v*)(w1 + 32);
  B1[2] = *(const h8v*)(w1 + 64); B1[3] = *(const h8v*)(w1 + 96);
}

// Run nLvl levels in LDS. S: n0 summed-child rows (f16, halves >=100 zero).
// Per level: MFMA -> H (relu, f16 packed), barrier, pairsum H->S + proj, barrier.
__device__ __forceinline__ void run_levels(
    _Float16* S, _Float16* H, const float* WpS,
    const h8v (&B0)[4], const h8v (&B1)[4], float bias0, float bias1,
    int firstLvl, int nLvl, int n0, int blk,
    const float* __restrict__ bp, float* __restrict__ out,
    int tid, int lane, int wave) {
  const int quad = lane >> 4, c16 = lane & 15;
  const int ct0 = wave * 2, ct1 = ct0 + 1;
  unsigned* Hd = (unsigned*)H;
  unsigned* Sd = (unsigned*)S;
  int n = n0;
  for (int j = 0; j < nLvl; ++j) {
    int lvl = firstLvl + j;
    int tiles = (n + 15) >> 4;
    for (int rt = 0; rt < tiles; ++rt) {
      int rb = rt << 4;
      const _Float16* arow = S + (rb + c16) * RS + quad * 8;
      h8v A0 = *(const h8v*)(arow);
      h8v A1 = *(const h8v*)(arow + 32);
      h8v A2 = *(const h8v*)(arow + 64);
      h8v A3 = *(const h8v*)(arow + 96);
      f4v acc0 = {bias0, bias0, bias0, bias0};
      f4v acc1 = {bias1, bias1, bias1, bias1};
      acc0 = __builtin_amdgcn_mfma_f32_16x16x32_f16(A0, B0[0], acc0, 0, 0, 0);
      acc0 = __builtin_amdgcn_mfma_f32_16x16x32_f16(A1, B0[1], acc0, 0, 0, 0);
      acc0 = __builtin_amdgcn_mfma_f32_16x16x32_f16(A2, B0[2], acc0, 0, 0, 0);
      acc0 = __builtin_amdgcn_mfma_f32_16x16x32_f16(A3, B0[3], acc0, 0, 0, 0);
      acc1 = __builtin_amdgcn_mfma_f32_16x16x32_f16(A0, B1[0], acc1, 0, 0, 0);
      acc1 = __builtin_amdgcn_mfma_f32_16x16x32_f16(A1, B1[1], acc1, 0, 0, 0);
      acc1 = __builtin_amdgcn_mfma_f32_16x16x32_f16(A2, B1[2], acc1, 0, 0, 0);
      acc1 = __builtin_amdgcn_mfma_f32_16x16x32_f16(A3, B1[3], acc1, 0, 0, 0);
      #pragma unroll
      for (int rg = 0; rg < 4; ++rg) {
        float v0 = fmaxf(acc0[rg], 0.f);
        float v1 = fmaxf(acc1[rg], 0.f);
        unsigned h0 = (unsigned)__builtin_bit_cast(unsigned short, (_Float16)v0);
        unsigned h1 = (unsigned)__builtin_bit_cast(unsigned short, (_Float16)v1);
        unsigned p0 = __shfl_xor(h0, 1, 64);
        unsigned p1 = __shfl_xor(h1, 1, 64);
        if ((c16 & 1) == 0) {
          int row = rb + quad * 4 + rg;
          Hd[row * RSD + ct0 * 8 + (c16 >> 1)] = h0 | (p0 << 16);
          Hd[row * RSD + ct1 * 8 + (c16 >> 1)] = h1 | (p1 << 16);
        }
      }
    }
    __syncthreads();
    if (n > 1) {
      int nn = n >> 1;
      for (int i = tid; i < nn * 64; i += 256) {
        int nd = i >> 6, d = i & 63;
        Sd[nd * RSD + d] = pkadd(Hd[(2 * nd) * RSD + d], Hd[(2 * nd + 1) * RSD + d]);
      }
    }
    if (tid < n) {
      const unsigned* hr = Hd + tid * RSD;
      float q0 = bp[0], q1 = bp[1];
      for (int p = 0; p < 50; ++p) {
        float2 h2 = upk(hr[p]);
        q0 = fmaf(h2.x, WpS[2 * p], fmaf(h2.y, WpS[2 * p + 1], q0));
        q1 = fmaf(h2.x, WpS[100 + 2 * p], fmaf(h2.y, WpS[100 + 2 * p + 1], q1));
      }
      long g = (long)blk * n + tid;
      long pos = ((g + 1) << (lvl + 1)) - 2 - __popc((unsigned)g);
      out[2 * pos] = q0; out[2 * pos + 1] = q1;
    }
    __syncthreads();
    n >>= 1;
  }
}

// Leaf kernel: 256 leaves/block. Lvl-0 proj (fp32, chunked) + levels 1..8 MFMA.
__global__ __launch_bounds__(256) void leaf_kernel(
    const int* __restrict__ word_ids, const float* __restrict__ emb,
    const unsigned short* __restrict__ Wlf, const float* __restrict__ bl,
    const float* __restrict__ Wp, const float* __restrict__ bp,
    unsigned* __restrict__ h8g, float* __restrict__ out) {
  __shared__ _Float16 S[128 * RS];
  __shared__ _Float16 H[128 * RS];
  __shared__ float WpS[200];
  const int tid = threadIdx.x, lane = tid & 63;
  const int wave = __builtin_amdgcn_readfirstlane(tid >> 6);
  const int quad = lane >> 4, c16 = lane & 15;
  const int blk = blockIdx.x;
  unsigned* Sd = (unsigned*)S;

  if (tid < 200) WpS[tid] = Wp[tid];
  for (int i = tid; i < 128 * 14; i += 256)        // zero pad dwords 50..63
    Sd[(i / 14) * RSD + 50 + (i % 14)] = 0;
  __syncthreads();

  // chunked leaf processing: proj + pair-sum + f16 pack, 8 VGPRs live
  int g = blk * 256 + tid;
  const float4* row4 = (const float4*)(emb + (size_t)word_ids[g] * 100);
  float q0 = bp[0], q1 = bp[1];
  #pragma unroll
  for (int q = 0; q < 25; ++q) {
    float4 v = row4[q];
    q0 = fmaf(v.x, WpS[4*q+0], q0); q0 = fmaf(v.y, WpS[4*q+1], q0);
    q0 = fmaf(v.z, WpS[4*q+2], q0); q0 = fmaf(v.w, WpS[4*q+3], q0);
    q1 = fmaf(v.x, WpS[100+4*q+0], q1); q1 = fmaf(v.y, WpS[100+4*q+1], q1);
    q1 = fmaf(v.z, WpS[100+4*q+2], q1); q1 = fmaf(v.w, WpS[100+4*q+3], q1);
    float sx = v.x + __shfl_xor(v.x, 1, 64);
    float sy = v.y + __shfl_xor(v.y, 1, 64);
    float sz = v.z + __shfl_xor(v.z, 1, 64);
    float sw = v.w + __shfl_xor(v.w, 1, 64);
    if ((tid & 1) == 0) {
      uint2 pr; pr.x = pk2f(sx, sy); pr.y = pk2f(sz, sw);
      *(uint2*)(Sd + (tid >> 1) * RSD + 2 * q) = pr;
    }
  }
  long pos0 = 2L * g - __popc((unsigned)g);
  out[2 * pos0] = q0; out[2 * pos0 + 1] = q1;

  h8v B0[4], B1[4]; float bias0, bias1;
  load_bfrags(Wlf, bl, B0, B1, bias0, bias1, wave, quad, c16);
  __syncthreads();

  run_levels(S, H, WpS, B0, B1, bias0, bias1, 1, 8, 128, blk, bp, out, tid, lane, wave);

  unsigned* Hd = (unsigned*)H;
  if (tid < 56) h8g[blk * 56 + tid] = Hd[tid];   // lvl-8 row
}

// Tree kernel: block reads 2*n0 packed rows, pairsums, runs nLvl levels.
__global__ __launch_bounds__(256) void tree_kernel(
    const unsigned* __restrict__ hsrc, unsigned* __restrict__ hdst,
    const unsigned short* __restrict__ Wlf, const float* __restrict__ bl,
    const float* __restrict__ Wp, const float* __restrict__ bp,
    float* __restrict__ out, int firstLvl, int nLvl, int n0, int wantH) {
  __shared__ _Float16 S[64 * RS];
  __shared__ _Float16 H[64 * RS];
  __shared__ float WpS[200];
  const int tid = threadIdx.x, lane = tid & 63;
  const int wave = __builtin_amdgcn_readfirstlane(tid >> 6);
  const int quad = lane >> 4, c16 = lane & 15;
  const int blk = blockIdx.x;
  unsigned* Sd = (unsigned*)S;

  if (tid < 200) WpS[tid] = Wp[tid];
  for (int i = tid; i < 64 * 8; i += 256)          // zero pad dwords 56..63
    Sd[(i >> 3) * RSD + 56 + (i & 7)] = 0;
  if (n0 < 16) {                                   // zero unused MFMA rows
    for (int i = tid; i < (16 - n0) * 56; i += 256)
      Sd[(n0 + i / 56) * RSD + (i % 56)] = 0;
  }
  for (int i = tid; i < n0 * 56; i += 256) {
    int nd = i / 56, d = i - nd * 56;
    Sd[nd * RSD + d] = pkadd(hsrc[((size_t)blk * 2 * n0 + 2 * nd) * 56 + d],
                             hsrc[((size_t)blk * 2 * n0 + 2 * nd + 1) * 56 + d]);
  }

  h8v B0[4], B1[4]; float bias0, bias1;
  load_bfrags(Wlf, bl, B0, B1, bias0, bias1, wave, quad, c16);
  __syncthreads();

  run_levels(S, H, WpS, B0, B1, bias0, bias1, firstLvl, nLvl, n0, blk, bp, out, tid, lane, wave);

  if (wantH) {
    int R = n0 >> (nLvl - 1);
    unsigned* Hd = (unsigned*)H;
    for (int i = tid; i < R * 56; i += 256)
      hdst[(size_t)blk * R * 56 + i] = Hd[(i / 56) * RSD + (i % 56)];
  }
}

extern "C" void kernel_launch(void* const* d_in, const int* in_sizes, int n_in,
                              void* d_out, int out_size, void* d_ws, size_t ws_size,
                              hipStream_t stream) {
  const int*   word_ids = (const int*)  d_in[0];
  const float* emb      = (const float*)d_in[1];
  const float* Wl       = (const float*)d_in[2];
  const float* bl       = (const float*)d_in[3];
  const float* Wp       = (const float*)d_in[4];
  const float* bp       = (const float*)d_in[5];
  float* out = (float*)d_out;

  unsigned short* Wlf = (unsigned short*)d_ws;                    // 32768 B
  unsigned* h8  = (unsigned*)((char*)d_ws + 32768);               // 512*56 dw
  unsigned* h15 = (unsigned*)((char*)d_ws + 32768 + 131072);      // 4*56 dw

  prep_kernel<<<64, 256, 0, stream>>>(Wl, Wlf);
  // lvls 0..8: 512 blocks x 256 leaves -> h8 (512 rows)
  leaf_kernel<<<512, 256, 0, stream>>>(word_ids, emb, Wlf, bl, Wp, bp, h8, out);
  // lvls 9..15: 4 blocks x 64 lvl-9 nodes -> h15 (4 rows)
  tree_kernel<<<4, 256, 0, stream>>>(h8, h15, Wlf, bl, Wp, bp, out, 9, 7, 64, 1);
  // lvls 16..17: 1 block x 2 lvl-16 nodes
  tree_kernel<<<1, 256, 0, stream>>>(h15, nullptr, Wlf, bl, Wp, bp, out, 16, 2, 2, 0);
}

// Round 8
// 152.154 us; speedup vs baseline: 7.2570x; 1.1400x over previous
//
#include <hip/hip_runtime.h>

typedef _Float16 h8v __attribute__((ext_vector_type(8)));
typedef float f4v __attribute__((ext_vector_type(4)));

#define RS 136   // halves per LDS row (272 B, 16B-aligned, stride%32dw==4 -> 2-way max)
#define SD 68    // dwords per row

__device__ __forceinline__ unsigned pk2f(float a, float b) {
  unsigned short ha = __builtin_bit_cast(unsigned short, (_Float16)a);
  unsigned short hb = __builtin_bit_cast(unsigned short, (_Float16)b);
  return (unsigned)ha | ((unsigned)hb << 16);
}
__device__ __forceinline__ float2 upk(unsigned u) {
  _Float16 lo = __builtin_bit_cast(_Float16, (unsigned short)(u & 0xffffu));
  _Float16 hi = __builtin_bit_cast(_Float16, (unsigned short)(u >> 16));
  return make_float2((float)lo, (float)hi);
}

// Wlf[o*128 + k] = f16(Wl[o][k]), zero-padded to [128][128]
__global__ void prep_kernel(const float* __restrict__ Wl,
                            unsigned short* __restrict__ Wlf) {
  int i = blockIdx.x * 256 + threadIdx.x;
  if (i < 128 * 128) {
    int o = i >> 7, k = i & 127;
    _Float16 v = (_Float16)0.f;
    if (o < 100 && k < 100) v = (_Float16)Wl[o * 100 + k];
    Wlf[i] = __builtin_bit_cast(unsigned short, v);
  }
}

__device__ __forceinline__ void load_bfrags(
    const unsigned short* __restrict__ Wlf, const float* __restrict__ bl,
    h8v (&B0)[4], h8v (&B1)[4], float& bias0, float& bias1,
    int wave, int quad, int c16) {
  int col0 = wave * 32 + c16;
  int col1 = col0 + 16;
  bias0 = (col0 < 100) ? 2.0f * bl[col0] : 0.f;
  bias1 = (col1 < 100) ? 2.0f * bl[col1] : 0.f;
  const _Float16* w0 = (const _Float16*)Wlf + col0 * 128 + quad * 8;
  const _Float16* w1 = (const _Float16*)Wlf + col1 * 128 + quad * 8;
  B0[0] = *(const h8v*)(w0);      B0[1] = *(const h8v*)(w0 + 32);
  B0[2] = *(const h8v*)(w0 + 64); B0[3] = *(const h8v*)(w0 + 96);
  B1[0] = *(const h8v*)(w1);      B1[1] = *(const h8v*)(w1 + 32);
  B1[2] = *(const h8v*)(w1 + 64); B1[3] = *(const h8v*)(w1 + 96);
}

// One level: nOut rows. pairMode: A = srcE[r] + srcO[r] (children 2r,2r+1);
// else A = srcE[r] (pre-summed). Output row -> (row&1 ? dstO : dstE)[row>>1].
__device__ __forceinline__ void mfma_level(
    const _Float16* srcE, const _Float16* srcO, bool pairMode,
    _Float16* dstE, _Float16* dstO, int nOut,
    const h8v (&B0)[4], const h8v (&B1)[4], float bias0, float bias1,
    int lane, int wave) {
  const int quad = lane >> 4, c16 = lane & 15;
  const int col0 = wave * 32 + c16, col1 = col0 + 16;
  const int tiles = (nOut + 15) >> 4;
  for (int rt = 0; rt < tiles; ++rt) {
    const int r = rt * 16 + c16;
    const h8v* pe = (const h8v*)(srcE + (size_t)r * RS + quad * 8);
    h8v A0, A1, A2, A3;
    if (pairMode) {
      const h8v* po = (const h8v*)(srcO + (size_t)r * RS + quad * 8);
      A0 = pe[0] + po[0];  A1 = pe[4] + po[4];
      A2 = pe[8] + po[8];  A3 = pe[12] + po[12];
    } else {
      A0 = pe[0]; A1 = pe[4]; A2 = pe[8]; A3 = pe[12];
    }
    f4v a0 = {bias0, bias0, bias0, bias0};
    f4v a1 = {bias1, bias1, bias1, bias1};
    a0 = __builtin_amdgcn_mfma_f32_16x16x32_f16(A0, B0[0], a0, 0, 0, 0);
    a0 = __builtin_amdgcn_mfma_f32_16x16x32_f16(A1, B0[1], a0, 0, 0, 0);
    a0 = __builtin_amdgcn_mfma_f32_16x16x32_f16(A2, B0[2], a0, 0, 0, 0);
    a0 = __builtin_amdgcn_mfma_f32_16x16x32_f16(A3, B0[3], a0, 0, 0, 0);
    a1 = __builtin_amdgcn_mfma_f32_16x16x32_f16(A0, B1[0], a1, 0, 0, 0);
    a1 = __builtin_amdgcn_mfma_f32_16x16x32_f16(A1, B1[1], a1, 0, 0, 0);
    a1 = __builtin_amdgcn_mfma_f32_16x16x32_f16(A2, B1[2], a1, 0, 0, 0);
    a1 = __builtin_amdgcn_mfma_f32_16x16x32_f16(A3, B1[3], a1, 0, 0, 0);
    #pragma unroll
    for (int rg = 0; rg < 4; ++rg) {
      int row = rt * 16 + quad * 4 + rg;
      _Float16* dr = ((row & 1) ? dstO : dstE) + (size_t)(row >> 1) * RS;
      dr[col0] = (_Float16)fmaxf(a0[rg], 0.f);
      dr[col1] = (_Float16)fmaxf(a1[rg], 0.f);
    }
  }
}

// Projection of nRows h-rows (E/O split) at level lvl, nodes gbase+tid.
__device__ __forceinline__ void proj_rows(
    const _Float16* E, const _Float16* O, int nRows, const float* WpS,
    float bp0, float bp1, int lvl, long gbase, float* __restrict__ out, int tid) {
  if (tid >= nRows) return;
  const unsigned* row = (const unsigned*)((tid & 1) ? O : E) + (size_t)(tid >> 1) * SD;
  float q0 = bp0, q1 = bp1;
  #pragma unroll
  for (int p = 0; p < 25; ++p) {
    uint2 u = ((const uint2*)row)[p];
    float2 a = upk(u.x), b = upk(u.y);
    q0 = fmaf(a.x, WpS[4*p], fmaf(a.y, WpS[4*p+1],
         fmaf(b.x, WpS[4*p+2], fmaf(b.y, WpS[4*p+3], q0))));
    q1 = fmaf(a.x, WpS[100+4*p], fmaf(a.y, WpS[100+4*p+1],
         fmaf(b.x, WpS[100+4*p+2], fmaf(b.y, WpS[100+4*p+3], q1))));
  }
  long g = gbase + tid;
  long pos = ((g + 1) << (lvl + 1)) - 2 - __popc((unsigned)g);
  out[2 * pos] = q0; out[2 * pos + 1] = q1;
}

// Leaf kernel: 128 leaves/block, levels 0..7; writes 1 h7 row (50 dw) per block.
__global__ __launch_bounds__(256, 3) void leaf_kernel(
    const int* __restrict__ word_ids, const float* __restrict__ emb,
    const unsigned short* __restrict__ Wlf, const float* __restrict__ bl,
    const float* __restrict__ Wp, const float* __restrict__ bp,
    unsigned* __restrict__ h7g, float* __restrict__ out) {
  __shared__ _Float16 S1[64 * RS];
  __shared__ _Float16 Ea[32 * RS], Oa[32 * RS];
  __shared__ _Float16 Eb[16 * RS], Ob[16 * RS];
  __shared__ float WpS[200];
  const int tid = threadIdx.x, lane = tid & 63;
  const int wave = __builtin_amdgcn_readfirstlane(tid >> 6);
  const int quad = lane >> 4, c16 = lane & 15;
  const int blk = blockIdx.x;

  if (tid < 200) WpS[tid] = Wp[tid];
  {   // zero S1 pad dwords 50..63
    unsigned* S1d = (unsigned*)S1;
    for (int i = tid; i < 64 * 14; i += 256) S1d[(i / 14) * SD + 50 + (i % 14)] = 0;
  }
  const float bp0 = bp[0], bp1 = bp[1];

  // gather: thread = (leaf l = tid>>1, half h = tid&1), 13/12 float4 each
  const int l = tid >> 1, hh = tid & 1;
  const long gL = (long)blk * 128 + l;
  const float4* row4 = (const float4*)(emb + (size_t)word_ids[gL] * 100);
  float4 v[13];
  #pragma unroll
  for (int i = 0; i < 13; ++i) {
    int q = 13 * hh + i;
    if (q < 25) v[i] = row4[q];
  }
  __syncthreads();   // WpS / S1-pad ready; v in flight or arrived

  {   // lvl-0 projection (fp32 inputs, exact)
    float q0 = 0.f, q1 = 0.f;
    #pragma unroll
    for (int i = 0; i < 13; ++i) {
      int q = 13 * hh + i;
      if (q < 25) {
        q0 = fmaf(v[i].x, WpS[4*q], fmaf(v[i].y, WpS[4*q+1],
             fmaf(v[i].z, WpS[4*q+2], fmaf(v[i].w, WpS[4*q+3], q0))));
        q1 = fmaf(v[i].x, WpS[100+4*q], fmaf(v[i].y, WpS[100+4*q+1],
             fmaf(v[i].z, WpS[100+4*q+2], fmaf(v[i].w, WpS[100+4*q+3], q1))));
      }
    }
    q0 += __shfl_xor(q0, 1, 64);
    q1 += __shfl_xor(q1, 1, 64);
    if (hh == 0) {
      long pos = ((gL + 1) << 1) - 2 - __popc((unsigned)gL);
      out[2 * pos] = q0 + bp0; out[2 * pos + 1] = q1 + bp1;
    }
  }
  {   // pair-sum with sibling leaf (xor 2) -> S1 rows (f16 packed)
    unsigned* S1d = (unsigned*)S1;
    #pragma unroll
    for (int i = 0; i < 13; ++i) {
      int q = 13 * hh + i;
      if (q < 25) {
        float sx = v[i].x + __shfl_xor(v[i].x, 2, 64);
        float sy = v[i].y + __shfl_xor(v[i].y, 2, 64);
        float sz = v[i].z + __shfl_xor(v[i].z, 2, 64);
        float sw = v[i].w + __shfl_xor(v[i].w, 2, 64);
        if ((tid & 2) == 0) {
          int m = tid >> 2;
          S1d[m * SD + 2*q]     = pk2f(sx, sy);
          S1d[m * SD + 2*q + 1] = pk2f(sz, sw);
        }
      }
    }
  }
  h8v B0[4], B1[4]; float bias0, bias1;
  load_bfrags(Wlf, bl, B0, B1, bias0, bias1, wave, quad, c16);
  __syncthreads();

  // L1 (64 out)
  mfma_level(S1, nullptr, false, Ea, Oa, 64, B0, B1, bias0, bias1, lane, wave);
  __syncthreads();
  // L2 (32) + proj l1
  mfma_level(Ea, Oa, true, Eb, Ob, 32, B0, B1, bias0, bias1, lane, wave);
  proj_rows(Ea, Oa, 64, WpS, bp0, bp1, 1, (long)blk * 64, out, tid);
  __syncthreads();
  // L3 (16) + proj l2
  mfma_level(Eb, Ob, true, Ea, Oa, 16, B0, B1, bias0, bias1, lane, wave);
  proj_rows(Eb, Ob, 32, WpS, bp0, bp1, 2, (long)blk * 32, out, tid);
  __syncthreads();
  // L4 (8) + proj l3
  mfma_level(Ea, Oa, true, Eb, Ob, 8, B0, B1, bias0, bias1, lane, wave);
  proj_rows(Ea, Oa, 16, WpS, bp0, bp1, 3, (long)blk * 16, out, tid);
  __syncthreads();
  // L5 (4) + proj l4
  mfma_level(Eb, Ob, true, Ea, Oa, 4, B0, B1, bias0, bias1, lane, wave);
  proj_rows(Eb, Ob, 8, WpS, bp0, bp1, 4, (long)blk * 8, out, tid);
  __syncthreads();
  // L6 (2) + proj l5
  mfma_level(Ea, Oa, true, Eb, Ob, 2, B0, B1, bias0, bias1, lane, wave);
  proj_rows(Ea, Oa, 4, WpS, bp0, bp1, 5, (long)blk * 4, out, tid);
  __syncthreads();
  // L7 (1) + proj l6
  mfma_level(Eb, Ob, true, Ea, Oa, 1, B0, B1, bias0, bias1, lane, wave);
  proj_rows(Eb, Ob, 2, WpS, bp0, bp1, 6, (long)blk * 2, out, tid);
  __syncthreads();
  // write h7 row (row 0 -> Ea idx 0); proj l7 happens in tree kernel
  if (tid < 50) h7g[(size_t)blk * 50 + tid] = ((unsigned*)Ea)[tid];
}

// Tree kernel: stages nIn rows (E/O), projs them at firstLvl-1, runs nLvl levels.
__global__ __launch_bounds__(256) void tree_kernel(
    const unsigned* __restrict__ hsrc, unsigned* __restrict__ hdst,
    const unsigned short* __restrict__ Wlf, const float* __restrict__ bl,
    const float* __restrict__ Wp, const float* __restrict__ bp,
    float* __restrict__ out, int firstLvl, int nLvl, int nIn, int finalProj) {
  __shared__ _Float16 Ea[32 * RS], Oa[32 * RS];
  __shared__ _Float16 Eb[16 * RS], Ob[16 * RS];
  __shared__ float WpS[200];
  const int tid = threadIdx.x, lane = tid & 63;
  const int wave = __builtin_amdgcn_readfirstlane(tid >> 6);
  const int quad = lane >> 4, c16 = lane & 15;
  const int blk = blockIdx.x;

  if (tid < 200) WpS[tid] = Wp[tid];
  const float bp0 = bp[0], bp1 = bp[1];

  {   // stage nIn rows + zero everything else in Ea/Oa (64 virtual rows x 64 dw)
    const unsigned* src = hsrc + (size_t)blk * nIn * 50;
    unsigned* Ed = (unsigned*)Ea; unsigned* Od = (unsigned*)Oa;
    for (int i = tid; i < 64 * 64; i += 256) {
      int r = i >> 6, d = i & 63;
      unsigned val = (r < nIn && d < 50) ? src[(size_t)r * 50 + d] : 0u;
      ((r & 1) ? Od : Ed)[(r >> 1) * SD + d] = val;
    }
    // zero Eb/Ob fully (32 virtual rows x 64 dw)
    unsigned* Ed2 = (unsigned*)Eb; unsigned* Od2 = (unsigned*)Ob;
    for (int i = tid; i < 32 * 64; i += 256) {
      int r = i >> 6, d = i & 63;
      ((r & 1) ? Od2 : Ed2)[(r >> 1) * SD + d] = 0u;
    }
  }
  h8v B0[4], B1[4]; float bias0, bias1;
  load_bfrags(Wlf, bl, B0, B1, bias0, bias1, wave, quad, c16);
  __syncthreads();

  _Float16 *sE = Ea, *sO = Oa, *dE = Eb, *dO = Ob;
  int n = nIn >> 1;
  for (int p = 0; p < nLvl; ++p) {
    mfma_level(sE, sO, true, dE, dO, n, B0, B1, bias0, bias1, lane, wave);
    proj_rows(sE, sO, n * 2, WpS, bp0, bp1, firstLvl + p - 1,
              (long)blk * (n * 2), out, tid);
    __syncthreads();
    _Float16* t;
    t = sE; sE = dE; dE = t;
    t = sO; sO = dO; dO = t;
    n >>= 1;
  }
  int R = nIn >> nLvl;
  if (finalProj)
    proj_rows(sE, sO, R, WpS, bp0, bp1, firstLvl + nLvl - 1, (long)blk * R, out, tid);
  if (hdst) {
    for (int i = tid; i < R * 50; i += 256) {
      int r = i / 50, d = i % 50;
      hdst[(size_t)blk * R * 50 + i] =
          ((const unsigned*)((r & 1) ? sO : sE))[(r >> 1) * SD + d];
    }
  }
}

extern "C" void kernel_launch(void* const* d_in, const int* in_sizes, int n_in,
                              void* d_out, int out_size, void* d_ws, size_t ws_size,
                              hipStream_t stream) {
  const int*   word_ids = (const int*)  d_in[0];
  const float* emb      = (const float*)d_in[1];
  const float* Wl       = (const float*)d_in[2];
  const float* bl       = (const float*)d_in[3];
  const float* Wp       = (const float*)d_in[4];
  const float* bp       = (const float*)d_in[5];
  float* out = (float*)d_out;

  unsigned short* Wlf = (unsigned short*)d_ws;                       // 32 KB
  unsigned* h7g  = (unsigned*)((char*)d_ws + 32768);                 // 1024*50 dw
  unsigned* h13g = (unsigned*)((char*)d_ws + 32768 + 204800);        // 16*50 dw

  prep_kernel<<<64, 256, 0, stream>>>(Wl, Wlf);
  // levels 0..7: 1024 blocks x 128 leaves -> h7g (1024 rows)
  leaf_kernel<<<1024, 256, 0, stream>>>(word_ids, emb, Wlf, bl, Wp, bp, h7g, out);
  // levels 8..13 (+ proj l7): 16 blocks x 64 h7 rows -> h13g (16 rows)
  tree_kernel<<<16, 256, 0, stream>>>(h7g, h13g, Wlf, bl, Wp, bp, out, 8, 6, 64, 0);
  // levels 14..17 (+ proj l13 + final proj l17): 1 block x 16 h13 rows
  tree_kernel<<<1, 256, 0, stream>>>(h13g, nullptr, Wlf, bl, Wp, bp, out, 14, 4, 16, 1);
}